// Round 29
// baseline (180.180 us; speedup 1.0000x reference)
//
#include <hip/hip_runtime.h>
#include <math.h>

// Shapes (fixed by the problem)
#define DIMC  1024
#define NHEAD 16
#define HD    64
#define NB    4
#define NX    1024
#define NC    2048
#define KD    1024

typedef _Float16 half_t;
typedef __attribute__((ext_vector_type(8))) _Float16 h8;
typedef __attribute__((ext_vector_type(4))) _Float16 h4;
typedef __attribute__((ext_vector_type(2))) __fp16 fp16x2;   // cvt_pkrtz's type
typedef __attribute__((ext_vector_type(4))) float f32x4;

// score prescale: 1/sqrt(64) * log2(e), so exp(s) == exp2(prescaled s)
#define QSCALE 0.1803368801111244f
// fixed softmax shift (ln units: 6) in exp2 units: 6*log2(e)
#define NEGM  -8.656170245333781f

__device__ __forceinline__ void gload_lds16(const half_t* g, half_t* l) {
    __builtin_amdgcn_global_load_lds(
        (__attribute__((address_space(1))) void*)(g),
        (__attribute__((address_space(3))) void*)(l), 16, 0, 0);
}

// ---------------------------------------------------------------------------
// Merged preprocessing: weight transposes (blocks 0..1023), fp32->fp16
// input convert (1024..7167; x AND c written as pre-swizzled 256x64 K-tile
// A-images), cos/sin tables (7168..7935). Wq and Wkv written as B-images.
// Image layout: tile (rowtile, ktile) of 256 rows x 64 k; row r holds 8
// 16B slots, phys slot = logical ^ (r&7).
// ---------------------------------------------------------------------------
__device__ __forceinline__ void wtile(const float* __restrict__ W,
                                      half_t* __restrict__ Wt, int N, int IMG,
                                      int bx, int by, int t)
{
    __shared__ half_t T[64][72];
    const int k0 = by * 64, n0 = bx * 64;
    const int kr = t >> 2, c0 = (t & 3) << 4;
    const float* src = W + (size_t)(k0 + kr) * N + n0 + c0;
#pragma unroll
    for (int j = 0; j < 16; j += 4) {
        float4 v = *(const float4*)(src + j);
        T[c0 + j + 0][kr] = (half_t)v.x;
        T[c0 + j + 1][kr] = (half_t)v.y;
        T[c0 + j + 2][kr] = (half_t)v.z;
        T[c0 + j + 3][kr] = (half_t)v.w;
    }
    __syncthreads();
    const int nr = t >> 2, kc = (t & 3) << 4;
    if (!IMG) {
        half_t* dst = Wt + (size_t)(n0 + nr) * KD + k0 + kc;
        *(int4*)dst       = *(const int4*)&T[nr][kc];
        *(int4*)(dst + 8) = *(const int4*)&T[nr][kc + 8];
    } else {
        // B-image: row = out-col n, tile (ntile, kt=by), slot-XOR by row&7
        const int n = n0 + nr;
        const int ntile = n >> 8, rr = n & 255;
        const int s0 = kc >> 3;                   // logical slots s0, s0+1
        half_t* base = Wt + ((size_t)(ntile * 16 + by) * 256 + rr) * 64;
        *(int4*)(base + ((s0 ^ (rr & 7)) << 3))       = *(const int4*)&T[nr][kc];
        *(int4*)(base + (((s0 + 1) ^ (rr & 7)) << 3)) = *(const int4*)&T[nr][kc + 8];
    }
}

__global__ __launch_bounds__(256) void prep(
    const float* __restrict__ x, half_t* __restrict__ xh,
    const float* __restrict__ c, half_t* __restrict__ ch,
    const float* __restrict__ xpe, const float* __restrict__ cpe,
    float* __restrict__ xct, float* __restrict__ xst,
    float* __restrict__ cct, float* __restrict__ cst,
    const float* __restrict__ Wq,  half_t* __restrict__ Wqt,
    const float* __restrict__ Wkv, half_t* __restrict__ Wkt,
    const float* __restrict__ Wp,  half_t* __restrict__ Wpt)
{
    const int bid = blockIdx.x, t = threadIdx.x;
    if (bid < 1024) {
        if (bid < 256)      wtile(Wq,  Wqt, DIMC, 1,     bid & 15,         bid >> 4,         t);
        else if (bid < 768) wtile(Wkv, Wkt, 2 * DIMC, 1, (bid - 256) & 31, (bid - 256) >> 5, t);
        else                wtile(Wp,  Wpt, DIMC, 0,     (bid - 768) & 15, (bid - 768) >> 4, t);
    } else if (bid < 7168) {
        const int nx = NB * NX * DIMC;
        const int i = ((bid - 1024) * 256 + t) * 8;
        h8 o;
        if (i < nx) {
            const float* s = x + i;
            float4 a = *(const float4*)(s);
            float4 b = *(const float4*)(s + 4);
            o[0] = (half_t)a.x; o[1] = (half_t)a.y; o[2] = (half_t)a.z; o[3] = (half_t)a.w;
            o[4] = (half_t)b.x; o[5] = (half_t)b.y; o[6] = (half_t)b.z; o[7] = (half_t)b.w;
            // A-image for Q GEMM: tile (mt, kt), row r, slot-XOR
            const int R = i >> 10, k = i & 1023;
            const int mt = R >> 8, r = R & 255, kt = k >> 6, sl = (k & 63) >> 3;
            *(h8*)(xh + ((size_t)(mt * 16 + kt) * 256 + r) * 64 + ((sl ^ (r & 7)) << 3)) = o;
        } else {
            const int j = i - nx;                 // flat idx into c (8192 x 1024)
            const float* s = c + j;
            float4 a = *(const float4*)(s);
            float4 b = *(const float4*)(s + 4);
            o[0] = (half_t)a.x; o[1] = (half_t)a.y; o[2] = (half_t)a.z; o[3] = (half_t)a.w;
            o[4] = (half_t)b.x; o[5] = (half_t)b.y; o[6] = (half_t)b.z; o[7] = (half_t)b.w;
            const int R = j >> 10, k = j & 1023;
            const int mt = R >> 8, r = R & 255, kt = k >> 6, sl = (k & 63) >> 3;
            *(h8*)(ch + ((size_t)(mt * 16 + kt) * 256 + r) * 64 + ((sl ^ (r & 7)) << 3)) = o;
        }
    } else {
        const int i = (bid - 7168) * 256 + t;
        if (i < NX * HD) {
            const float th = xpe[i];
            xct[i] = cosf(th); xst[i] = sinf(th);
        } else {
            const int j = i - NX * HD;
            const float th = cpe[j];
            cct[j] = cosf(th); cst[j] = sinf(th);
        }
    }
}

// ---------------------------------------------------------------------------
// fp16 MFMA GEMM (proj only): BM=128, BK=64, 4 waves, dbuf + counted vmcnt.
// BN=64: 4x1 waves (32x64 each). MODE 2: + bias -> fp32 out row-major.
// ---------------------------------------------------------------------------
template <int MODE, int BN>
__global__ __launch_bounds__(256) void hgemm(
    const half_t* __restrict__ Ag, const half_t* __restrict__ Bt,
    const float* __restrict__ ct, const float* __restrict__ st,
    const float* __restrict__ bias,
    void* __restrict__ out0, void* __restrict__ out1)
{
    constexpr int MI = (BN == 128) ? 4 : 2;
    constexpr int BLOADS = BN / 32;
    __shared__ half_t As[2][8192];
    __shared__ half_t Bs[2][BN * 64];

    const int tid = threadIdx.x;
    const int w = tid >> 6, lane = tid & 63;
    const int lr = lane & 15, lg = lane >> 4;
    const int wrOff = (BN == 128) ? (w >> 1) * 64 : w * 32;
    const int wcOff = (BN == 128) ? (w & 1) * 64 : 0;

    int lin = (int)blockIdx.x;
    lin = (lin & 7) * ((int)gridDim.x >> 3) + (lin >> 3);
    const int m0 = (lin >> 4) * 128, n0 = (lin & 15) * BN;

    f32x4 acc[MI][4];
#pragma unroll
    for (int i = 0; i < MI; ++i)
#pragma unroll
        for (int j = 0; j < 4; ++j) acc[i][j] = f32x4{0.f, 0.f, 0.f, 0.f};

    size_t gA[4], gB[BLOADS];
    int loff[4];
#pragma unroll
    for (int c = 0; c < 4; ++c) {
        const int L = c * 4096 + w * 1024 + lane * 16;
        const int row = L >> 7;
        const int ss = ((L >> 4) & 7) ^ (row & 7);
        gA[c] = (size_t)(m0 + row) * KD + ss * 8;
        if (c < BLOADS) gB[c] = (size_t)(n0 + row) * KD + ss * 8;
        loff[c] = c * 2048 + w * 512;
    }

#define HSTAGE(buf, kk) do {                                               \
        _Pragma("unroll")                                                  \
        for (int c = 0; c < 4; ++c) {                                      \
            gload_lds16(Ag + gA[c] + (kk) * 64, &As[buf][loff[c]]);        \
            if (c < BLOADS) gload_lds16(Bt + gB[c] + (kk) * 64, &Bs[buf][loff[c]]); \
        }                                                                  \
    } while (0)

    HSTAGE(0, 0);
    asm volatile("s_waitcnt vmcnt(0)" ::: "memory");
    __builtin_amdgcn_s_barrier();
    __builtin_amdgcn_sched_barrier(0);

    for (int k = 0; k < KD / 64; ++k) {
        const int cb = k & 1;
        if (k + 1 < KD / 64) {
            HSTAGE(cb ^ 1, k + 1);
            if constexpr (BLOADS == 4)
                asm volatile("s_waitcnt vmcnt(8)" ::: "memory");
            else
                asm volatile("s_waitcnt vmcnt(6)" ::: "memory");
        } else {
            asm volatile("s_waitcnt vmcnt(0)" ::: "memory");
        }
        __builtin_amdgcn_s_barrier();
        __builtin_amdgcn_sched_barrier(0);

        __builtin_amdgcn_s_setprio(1);
#pragma unroll
        for (int kc = 0; kc < 2; ++kc) {
            h8 af[MI], bf[4];
#pragma unroll
            for (int mi = 0; mi < MI; ++mi) {
                const int r = wrOff + mi * 16 + lr;
                af[mi] = *(const h8*)&As[cb][r * 64 + (((kc * 4 + lg) ^ (r & 7)) << 3)];
            }
#pragma unroll
            for (int ni = 0; ni < 4; ++ni) {
                const int r = wcOff + ni * 16 + lr;
                bf[ni] = *(const h8*)&Bs[cb][r * 64 + (((kc * 4 + lg) ^ (r & 7)) << 3)];
            }
#pragma unroll
            for (int mi = 0; mi < MI; ++mi)
#pragma unroll
                for (int ni = 0; ni < 4; ++ni)
                    acc[mi][ni] = __builtin_amdgcn_mfma_f32_16x16x32_f16(
                        af[mi], bf[ni], acc[mi][ni], 0, 0, 0);
        }
        __builtin_amdgcn_s_setprio(0);

        __builtin_amdgcn_s_barrier();
        __builtin_amdgcn_sched_barrier(0);
    }
#undef HSTAGE

    if (MODE == 2) {
        float* o = (float*)out0;
#pragma unroll
        for (int ni = 0; ni < 4; ++ni) {
            const int col = n0 + ni * 16 + lr;
            const float bv = bias[col];
#pragma unroll
            for (int mi = 0; mi < MI; ++mi)
#pragma unroll
                for (int r = 0; r < 4; ++r) {
                    const int row = m0 + wrOff + mi * 16 + lg * 4 + r;
                    o[(size_t)row * DIMC + col] = acc[mi][ni][r] + bv;
                }
        }
    }
}

// ---------------------------------------------------------------------------
// MERGED GEMM v3.0: BM=256 x BN=128 tiles, 512 threads = 8 waves (4M x 2N,
// 64x64 out each). A double-buffered (32KB x2), B SINGLE-buffered (16KB).
// LDS 80KB -> 2 blocks/CU. Grid 640 = 512 KV + 128 Q blocks.
// v3.0: TWO phases per K-tile (16 MFMA each) -> 4 barriers/tile (was 8).
// Invariants preserved from validated v2.1:
//  - B WAR: bf(t) reads complete before PhaseA MFMA issue (compiler lgkmcnt
//    wait; bf is a PhaseA MFMA operand) -> before PhaseA trailing barrier ->
//    before any wave's B(t+1) issue in PhaseB. B staging must NOT move to
//    PhaseA (skewed waves' bf reads would race).
//  - A WAR: Ah0/Ah1(t+1) write ALT, last read tile t-1, fenced.
//  - RAW: full vmcnt(0) before tile-trailing barrier (per-wave A-half
//    consumption forbids counted gates here -- R25 lesson).
// ---------------------------------------------------------------------------
__global__ __launch_bounds__(512, 4) void hgemm_all(
    const half_t* __restrict__ Aimg, const half_t* __restrict__ Bimg,
    const half_t* __restrict__ Aq,   const half_t* __restrict__ Bq,
    const float* __restrict__ cct, const float* __restrict__ cst,
    const float* __restrict__ xct, const float* __restrict__ xst,
    half_t* __restrict__ Kw, half_t* __restrict__ Vw, half_t* __restrict__ Qw)
{
    __shared__ half_t lds[40960];   // 80 KB: A0@0, A1@16384, B@32768

    const int tid = threadIdx.x;
    const int w = tid >> 6, lane = tid & 63;
    const int lr = lane & 15, lg = lane >> 4;
    const int wr = w >> 1, wc = w & 1;
    const int wrOff = wr * 64, wcOff = wc * 64;

    const int bid = (int)blockIdx.x;
    const bool isQ = bid >= 512;
    int m0, n0;
    const half_t* Ablk;
    const half_t* Bblk;
    if (!isQ) {
        int lin = (bid & 7) * 64 + (bid >> 3);   // 512 blocks, bijective
        const int mt = lin >> 4, nt = lin & 15;
        m0 = mt * 256; n0 = nt * 128;
        Ablk = Aimg + (size_t)mt * 262144;
        Bblk = Bimg + (size_t)(nt >> 1) * 262144 + (size_t)(nt & 1) * 8192;
    } else {
        const int q = bid - 512;                 // 128 blocks
        int lin = (q & 7) * 16 + (q >> 3);       // bijective (128 % 8 == 0)
        const int mt = lin >> 3, nt = lin & 7;
        m0 = mt * 256; n0 = nt * 128;
        Ablk = Aq + (size_t)mt * 262144;
        Bblk = Bq + (size_t)(nt >> 1) * 262144 + (size_t)(nt & 1) * 8192;
    }
    const int so2 = w * 512 + lane * 8;

    f32x4 acc[4][4];
#pragma unroll
    for (int i = 0; i < 4; ++i)
#pragma unroll
        for (int j = 0; j < 4; ++j) acc[i][j] = f32x4{0.f, 0.f, 0.f, 0.f};
    h8 bf[4][2];    // [ni][kc], held per K-tile

// one 8KB chunk (512 thr x 16B) per call
#define ISSUEH(SRC, DSTOFF) do {                                     \
        gload_lds16((SRC) + so2,        &lds[(DSTOFF) + w * 512]);   \
        gload_lds16((SRC) + 4096 + so2, &lds[(DSTOFF) + 4096 + w * 512]); \
    } while (0)

// merged phase: two MI rows (MIa, MIb), 16 MFMA, 2 barriers
#define PHASE2(MIa, MIb, AOFF, READBF, STG, GATE) do {               \
        h8 afA[2], afB[2];                                           \
        {                                                            \
            const int rA = wrOff + (MIa) * 16 + lr;                  \
            const int rB = wrOff + (MIb) * 16 + lr;                  \
            _Pragma("unroll")                                        \
            for (int kc = 0; kc < 2; ++kc) {                         \
                afA[kc] = *(const h8*)&lds[(AOFF) + rA * 64 + (((kc * 4 + lg) ^ (rA & 7)) << 3)]; \
                afB[kc] = *(const h8*)&lds[(AOFF) + rB * 64 + (((kc * 4 + lg) ^ (rB & 7)) << 3)]; \
            }                                                        \
        }                                                            \
        if (READBF) {                                                \
            _Pragma("unroll")                                        \
            for (int ni = 0; ni < 4; ++ni)                           \
            _Pragma("unroll")                                        \
            for (int kc = 0; kc < 2; ++kc) {                         \
                const int rb = wcOff + ni * 16 + lr;                 \
                bf[ni][kc] = *(const h8*)&lds[32768 + rb * 64 + (((kc * 4 + lg) ^ (rb & 7)) << 3)]; \
            }                                                        \
        }                                                            \
        STG;                                                         \
        __builtin_amdgcn_sched_barrier(0);                           \
        __builtin_amdgcn_s_barrier();                                \
        __builtin_amdgcn_s_setprio(1);                               \
        _Pragma("unroll")                                            \
        for (int ni = 0; ni < 4; ++ni)                               \
        _Pragma("unroll")                                            \
        for (int kc = 0; kc < 2; ++kc) {                             \
            acc[(MIa)][ni] = __builtin_amdgcn_mfma_f32_16x16x32_f16( \
                afA[kc], bf[ni][kc], acc[(MIa)][ni], 0, 0, 0);       \
            acc[(MIb)][ni] = __builtin_amdgcn_mfma_f32_16x16x32_f16( \
                afB[kc], bf[ni][kc], acc[(MIb)][ni], 0, 0, 0);       \
        }                                                            \
        __builtin_amdgcn_s_setprio(0);                               \
        GATE;                                                        \
        __builtin_amdgcn_s_barrier();                                \
    } while (0)

#define GATE0 asm volatile("s_waitcnt vmcnt(0)" ::: "memory")
#define NOG   ((void)0)

    // prologue: A(0) -> A0 (2 chunks), B(0) -> B
    ISSUEH(Ablk, 0);
    ISSUEH(Ablk + 8192, 8192);
    ISSUEH(Bblk, 32768);
    asm volatile("s_waitcnt vmcnt(0)" ::: "memory");
    __builtin_amdgcn_s_barrier();
    __builtin_amdgcn_sched_barrier(0);

#pragma unroll 2
    for (int t = 0; t < 16; ++t) {
        const int AOFF = (t & 1) ? 16384 : 0;
        const int ALT  = (t & 1) ? 0 : 16384;
        const half_t* An = Ablk + (size_t)(t + 1) * 16384;
        const half_t* Bn = Bblk + (size_t)(t + 1) * 16384;
        const bool more = (t + 1 < 16);
        // v3.0: 2 phases x 16 MFMA. Staging split as in v2.1 (Ah0 first
        // phase; B+Ah1 second phase -- B must stay post-barrier-chain).
        PHASE2(0, 1, AOFF, true,  if (more) ISSUEH(An, ALT),               NOG);
        PHASE2(2, 3, AOFF, false,
               if (more) { ISSUEH(Bn, 32768); ISSUEH(An + 8192, ALT + 8192); },
               GATE0);
    }
#undef PHASE2
#undef ISSUEH
#undef GATE0
#undef NOG

    if (!isQ) {
        // KV epilogue: RoPE-K (cols < 1024) / V tile images for attention
        const bool isK = (n0 < DIMC);
        const int h = ((n0 & (DIMC - 1)) >> 6) + wc;
#pragma unroll
        for (int mi = 0; mi < 4; ++mi)
#pragma unroll
            for (int r = 0; r < 4; ++r) {
                const int row = m0 + wrOff + mi * 16 + lg * 4 + r;
                const int bb = row >> 11, nn = row & (NC - 1);
                const int tt = nn >> 6, rr = nn & 63;
                const size_t tbase = ((size_t)(bb * NHEAD + h) * 32 + tt) * 4096;
                const float* cr = cct + nn * HD;
                const float* sr = cst + nn * HD;
#pragma unroll
                for (int ni = 0; ni < 4; ++ni) {
                    const int d = ni * 16 + lr;
                    const float val = acc[mi][ni][r];
                    if (isK) {
                        const float pv = acc[mi][ni ^ 2][r];
                        Kw[tbase + rr * 64 + ((((d >> 3) ^ (rr & 7)) << 3) | (d & 7))] =
                            (half_t)(val * cr[d] + (ni < 2 ? -pv : pv) * sr[d]);
                    } else {
                        Vw[tbase + d * 64 + ((((rr >> 3) ^ (d & 7)) << 3) | (rr & 7))] =
                            (half_t)val;
                    }
                }
            }
    } else {
        // Q epilogue: RoPE * QSCALE -> fp16 (B, H, NX, HD)
        const int h = (n0 >> 6) + wc;
#pragma unroll
        for (int mi = 0; mi < 4; ++mi)
#pragma unroll
            for (int r = 0; r < 4; ++r) {
                const int row = m0 + wrOff + mi * 16 + lg * 4 + r;
                const int bb = row >> 10, nn = row & (NX - 1);
                const float* cr = xct + nn * HD;
                const float* sr = xst + nn * HD;
                half_t* op = Qw + (((size_t)(bb * NHEAD + h)) * NX + nn) * HD;
#pragma unroll
                for (int ni = 0; ni < 4; ++ni) {
                    const int d = ni * 16 + lr;
                    const float val = acc[mi][ni][r];
                    const float pv  = acc[mi][ni ^ 2][r];   // d ^ 32 partner
                    op[d] = (half_t)((val * cr[d] + (ni < 2 ? -pv : pv) * sr[d]) * QSCALE);
                }
            }
    }
}

// ---------------------------------------------------------------------------
// Swapped-operand MFMA flash attention (fp16), fixed-max softmax, kv-SPLIT,
// 4 waves, QBLK=256 (4 q-fragments/wave, K/V frags read once). 3-deep K/V
// ring, ONE barrier per tile. Partials out IN FP16 (halves the Opart
// round-trip traffic; |acc| << fp16 range).
// ---------------------------------------------------------------------------
__global__ __launch_bounds__(256) void attn_mfma(
    const half_t* __restrict__ Q, const half_t* __restrict__ Kg,
    const half_t* __restrict__ Vg,
    half_t* __restrict__ Opart, float* __restrict__ Lpart)
{
    __shared__ half_t Ks[3][4096];   // swizzled K tile image [kv][d]
    __shared__ half_t Vs[3][4096];   // swizzled V^T tile image [d][kv]
    __shared__ half_t Ps[16384];     // swizzled P [q(256)][kv], wave-private rows

    const int tid = threadIdx.x;
    const int w = tid >> 6, lane = tid & 63;
    const int lr = lane & 15, lg = lane >> 4;
    const int e7 = lr & 7;

    // kv half + XCD swizzle (both halves of a bh land on the same XCD)
    const int inner = (int)blockIdx.x & 255;
    const int kvh = (int)blockIdx.x >> 8;
    const int sid = (inner & 7) * 32 + (inner >> 3);
    const int bh = sid >> 2;
    const int q0 = (sid & 3) * 256;

    // Q fragments: qb in 0..3, rows q0 + qb*64 + w*16 + lr
    h8 qf0[4], qf1[4];
#pragma unroll
    for (int qb = 0; qb < 4; ++qb) {
        const half_t* qbase =
            Q + ((size_t)bh * NX + q0 + qb * 64 + w * 16 + lr) * HD + lg * 8;
        qf0[qb] = *(const h8*)(qbase);
        qf1[qb] = *(const h8*)(qbase + 32);
    }

    f32x4 acc[4][4];
#pragma unroll
    for (int qb = 0; qb < 4; ++qb)
#pragma unroll
        for (int i = 0; i < 4; ++i) acc[qb][i] = f32x4{0.f, 0.f, 0.f, 0.f};
    f32x4 accl[4];
#pragma unroll
    for (int qb = 0; qb < 4; ++qb) accl[qb] = f32x4{0.f, 0.f, 0.f, 0.f};

    h8 vone;
#pragma unroll
    for (int i = 0; i < 8; ++i) vone[i] = (half_t)(lr == 0 ? 1.0f : 0.0f);

    const half_t* Kt = Kg + (size_t)bh * 32 * 4096;
    const half_t* Vt = Vg + (size_t)bh * 32 * 4096;
    const int so = w * 512 + lane * 8;   // 256 thr cover 2048; two rounds/tile
    const int t0 = kvh * 16;

#define STAGE(bi, t) do {                                           \
        const half_t* kg_ = Kt + (size_t)(t) * 4096;                \
        const half_t* vg_ = Vt + (size_t)(t) * 4096;                \
        gload_lds16(kg_ + so,        &Ks[bi][w * 512]);             \
        gload_lds16(kg_ + 2048 + so, &Ks[bi][2048 + w * 512]);      \
        gload_lds16(vg_ + so,        &Vs[bi][w * 512]);             \
        gload_lds16(vg_ + 2048 + so, &Vs[bi][2048 + w * 512]);      \
    } while (0)

    // prologue: issue STAGE(tile 0) into buf 0 (no drain; gated in body 0)
    STAGE(0, t0);

    const int rowq = w * 16 + lr;     // base q row; qb adds qb*64

    int cur = 0, nxt = 1;
    for (int i = 0; i < 16; ++i) {
        if (i + 1 < 16) {
            STAGE(nxt, t0 + i + 1);
            asm volatile("s_waitcnt vmcnt(4)" ::: "memory");
        } else {
            asm volatile("s_waitcnt vmcnt(0)" ::: "memory");
        }
        __builtin_amdgcn_s_barrier();
        __builtin_amdgcn_sched_barrier(0);

        // K fragments read ONCE, reused for all 4 qb
        h8 kfr[4][2];
#pragma unroll
        for (int cb = 0; cb < 4; ++cb) {
            const int r = cb * 16 + lr;
            kfr[cb][0] = *(const h8*)&Ks[cur][r * 64 + ((lg ^ e7) << 3)];
            kfr[cb][1] = *(const h8*)&Ks[cur][r * 64 + (((4 + lg) ^ e7) << 3)];
        }

#pragma unroll
        for (int qb = 0; qb < 4; ++qb) {
            const int rowp = qb * 64 + rowq;

            // S^T = K Q^T, C-init = NEGM. Lane: q=lr, kv = cb*16+lg*4+r.
            f32x4 sc[4];
            __builtin_amdgcn_s_setprio(1);
#pragma unroll
            for (int cb = 0; cb < 4; ++cb) {
                f32x4 a = {NEGM, NEGM, NEGM, NEGM};
                a = __builtin_amdgcn_mfma_f32_16x16x32_f16(kfr[cb][0], qf0[qb], a, 0, 0, 0);
                a = __builtin_amdgcn_mfma_f32_16x16x32_f16(kfr[cb][1], qf1[qb], a, 0, 0, 0);
                sc[cb] = a;
            }
            __builtin_amdgcn_s_setprio(0);

            // p = exp2(s), packed to fp16; P^T -> Ps rows [rowp]
#pragma unroll
            for (int cb = 0; cb < 4; ++cb) {
                fp16x2 a01 = __builtin_amdgcn_cvt_pkrtz(exp2f(sc[cb][0]), exp2f(sc[cb][1]));
                fp16x2 a23 = __builtin_amdgcn_cvt_pkrtz(exp2f(sc[cb][2]), exp2f(sc[cb][3]));
                union { h4 h; uint2 u; } pw;
                pw.u.x = *(unsigned int*)&a01;
                pw.u.y = *(unsigned int*)&a23;
                const int s = cb * 2 + (lg >> 1);
                *(h4*)&Ps[rowp * 64 + ((s ^ e7) << 3) + (lg & 1) * 4] = pw.h;
            }
        }

        // P fragments for all qb; V fragments read once per db
        h8 pf0q[4], pf1q[4];
#pragma unroll
        for (int qb = 0; qb < 4; ++qb) {
            const int rowp = qb * 64 + rowq;
            pf0q[qb] = *(const h8*)&Ps[rowp * 64 + ((lg ^ e7) << 3)];
            pf1q[qb] = *(const h8*)&Ps[rowp * 64 + (((4 + lg) ^ e7) << 3)];
        }

        __builtin_amdgcn_s_setprio(1);
#pragma unroll
        for (int db = 0; db < 4; ++db) {
            const int rd = db * 16 + lr;
            const h8 vf0 = *(const h8*)&Vs[cur][rd * 64 + ((lg ^ e7) << 3)];
            const h8 vf1 = *(const h8*)&Vs[cur][rd * 64 + (((4 + lg) ^ e7) << 3)];
#pragma unroll
            for (int qb = 0; qb < 4; ++qb) {
                acc[qb][db] = __builtin_amdgcn_mfma_f32_16x16x32_f16(pf0q[qb], vf0, acc[qb][db], 0, 0, 0);
                acc[qb][db] = __builtin_amdgcn_mfma_f32_16x16x32_f16(pf1q[qb], vf1, acc[qb][db], 0, 0, 0);
            }
        }
#pragma unroll
        for (int qb = 0; qb < 4; ++qb) {
            accl[qb] = __builtin_amdgcn_mfma_f32_16x16x32_f16(pf0q[qb], vone, accl[qb], 0, 0, 0);
            accl[qb] = __builtin_amdgcn_mfma_f32_16x16x32_f16(pf1q[qb], vone, accl[qb], 0, 0, 0);
        }
        __builtin_amdgcn_s_setprio(0);

        // advance 3-deep ring (no end-of-tile barrier: WAR protected by the
        // pre-compute barrier one iteration later)
        cur = nxt;
        nxt = (nxt == 2) ? 0 : nxt + 1;
    }
#undef STAGE

    // write partials (fp16): per qb a 64q x 64d tile + f32 row sums (lr==0).
#pragma unroll
    for (int qb = 0; qb < 4; ++qb) {
        const int qblk = (q0 >> 6) + qb;
        const int slot = (bh * 16 + qblk) * 2 + kvh;
        half_t* Po = Opart + (size_t)slot * 4096;
#pragma unroll
        for (int db = 0; db < 4; ++db)
#pragma unroll
            for (int r = 0; r < 4; ++r)
                Po[(w * 16 + lg * 4 + r) * 64 + db * 16 + lr] = (half_t)acc[qb][db][r];
        if (lr == 0) {
#pragma unroll
            for (int r = 0; r < 4; ++r)
                Lpart[(size_t)slot * 64 + w * 16 + lg * 4 + r] = accl[qb][r];
        }
    }
}

// ---------------------------------------------------------------------------
// Combine: O = (P0 + P1) / (l0 + l1) -> Ow fp16 (B, NX, DIMC) layout.
// Partials are fp16. 1024 blocks, 256 threads, 16 outputs each.
// ---------------------------------------------------------------------------
__global__ __launch_bounds__(256) void combine(
    const half_t* __restrict__ Opart, const float* __restrict__ Lpart,
    half_t* __restrict__ Ow)
{
    const int pidx = blockIdx.x;              // bh*16 + qblk
    const int bh = pidx >> 4, qblk = pidx & 15;
    const int b = bh >> 4, h = bh & 15;
    const int t = threadIdx.x;
    const int row = t >> 2;                   // 0..63
    const int c0 = (t & 3) << 4;              // 0,16,32,48

    const half_t* P0 = Opart + (size_t)(pidx * 2 + 0) * 4096 + row * 64 + c0;
    const half_t* P1 = Opart + (size_t)(pidx * 2 + 1) * 4096 + row * 64 + c0;
    const float inv = 1.f / (Lpart[(size_t)(pidx * 2 + 0) * 64 + row] +
                             Lpart[(size_t)(pidx * 2 + 1) * 64 + row]);

    half_t* o = Ow + ((size_t)b * NX + qblk * 64 + row) * DIMC + h * 64 + c0;
#pragma unroll
    for (int j = 0; j < 16; j += 8) {
        h8 a = *(const h8*)(P0 + j);
        h8 bb = *(const h8*)(P1 + j);
        h8 ov;
#pragma unroll
        for (int k = 0; k < 8; ++k)
            ov[k] = (half_t)(((float)a[k] + (float)bb[k]) * inv);
        *(h8*)(o + j) = ov;
    }
}

// ---------------------------------------------------------------------------
extern "C" void kernel_launch(void* const* d_in, const int* in_sizes, int n_in,
                              void* d_out, int out_size, void* d_ws, size_t ws_size,
                              hipStream_t stream)
{
    const float* x     = (const float*)d_in[0];
    const float* c     = (const float*)d_in[1];
    const float* xpe   = (const float*)d_in[2];
    const float* cpe   = (const float*)d_in[3];
    const float* Wq    = (const float*)d_in[4];
    const float* Wkv   = (const float*)d_in[5];
    const float* Wproj = (const float*)d_in[6];
    const float* bproj = (const float*)d_in[7];

    char* wsb = (char*)d_ws;
    half_t* xh  = (half_t*)(wsb);                          // 8 MB  (A-image, dead by attn)
    half_t* ch  = (half_t*)(wsb + ((size_t)8  << 20));     // 16 MB (A-image, dead by attn)
    half_t* Wqt = (half_t*)(wsb + ((size_t)24 << 20));     // 2 MB  (B-image, dead by attn)
    half_t* Wkt = (half_t*)(wsb + ((size_t)26 << 20));     // 4 MB  (B-image, dead by attn)
    half_t* Kw  = (half_t*)(wsb + ((size_t)32 << 20));     // 16 MB (attn image)
    half_t* Vw  = (half_t*)(wsb + ((size_t)48 << 20));     // 16 MB (attn image)
    half_t* Ow  = (half_t*)(wsb + ((size_t)64 << 20));     // 8 MB
    float*  xct = (float*)(wsb + ((size_t)72 << 20));      // 256 KB
    float*  xst = (float*)(wsb + ((size_t)72 << 20) + (256u << 10));
    float*  cct = (float*)(wsb + ((size_t)72 << 20) + (512u << 10));
    float*  cst = (float*)(wsb + ((size_t)72 << 20) + (1024u << 10));
    half_t* Wpt = (half_t*)(wsb + ((size_t)74 << 20));     // 2 MB (live past attn)
    float*  Lpart = (float*)(wsb + ((size_t)76 << 20));    // 512 KB
    half_t* OpartH = (half_t*)(wsb);                       // 16 MB over dead xh/ch
    half_t* Qw  = (half_t*)d_out;   // attn consumes before hgemm<2> overwrites

    prep<<<7936, 256, 0, stream>>>(x, xh, c, ch, xpe, cpe,
                                   xct, xst, cct, cst,
                                   Wq, Wqt, Wkv, Wkt, Wproj, Wpt);

    hgemm_all<<<640, 512, 0, stream>>>(ch, Wkt, xh, Wqt,
                                       cct, cst, xct, xst,
                                       Kw, Vw, Qw);
    attn_mfma<<<512, 256, 0, stream>>>(Qw, Kw, Vw, OpartH, Lpart);
    combine<<<1024, 256, 0, stream>>>(OpartH, Lpart, Ow);
    hgemm<2, 64><<<512, 256, 0, stream>>>(Ow, Wpt, nullptr, nullptr, bproj,
                                          (float*)d_out, nullptr);
}

// Round 30
// 168.914 us; speedup vs baseline: 1.0667x; 1.0667x over previous
//
#include <hip/hip_runtime.h>
#include <math.h>

// Shapes (fixed by the problem)
#define DIMC  1024
#define NHEAD 16
#define HD    64
#define NB    4
#define NX    1024
#define NC    2048
#define KD    1024

typedef _Float16 half_t;
typedef __attribute__((ext_vector_type(8))) _Float16 h8;
typedef __attribute__((ext_vector_type(4))) _Float16 h4;
typedef __attribute__((ext_vector_type(2))) __fp16 fp16x2;   // cvt_pkrtz's type
typedef __attribute__((ext_vector_type(4))) float f32x4;

// score prescale: 1/sqrt(64) * log2(e), so exp(s) == exp2(prescaled s)
#define QSCALE 0.1803368801111244f
// fixed softmax shift (ln units: 6) in exp2 units: 6*log2(e)
#define NEGM  -8.656170245333781f

__device__ __forceinline__ void gload_lds16(const half_t* g, half_t* l) {
    __builtin_amdgcn_global_load_lds(
        (__attribute__((address_space(1))) void*)(g),
        (__attribute__((address_space(3))) void*)(l), 16, 0, 0);
}

// ---------------------------------------------------------------------------
// Merged preprocessing: weight transposes (blocks 0..1023), fp32->fp16
// input convert (1024..7167; x AND c written as pre-swizzled 256x64 K-tile
// A-images), cos/sin tables (7168..7935). Wq and Wkv written as B-images.
// Image layout: tile (rowtile, ktile) of 256 rows x 64 k; row r holds 8
// 16B slots, phys slot = logical ^ (r&7).
// ---------------------------------------------------------------------------
__device__ __forceinline__ void wtile(const float* __restrict__ W,
                                      half_t* __restrict__ Wt, int N, int IMG,
                                      int bx, int by, int t)
{
    __shared__ half_t T[64][72];
    const int k0 = by * 64, n0 = bx * 64;
    const int kr = t >> 2, c0 = (t & 3) << 4;
    const float* src = W + (size_t)(k0 + kr) * N + n0 + c0;
#pragma unroll
    for (int j = 0; j < 16; j += 4) {
        float4 v = *(const float4*)(src + j);
        T[c0 + j + 0][kr] = (half_t)v.x;
        T[c0 + j + 1][kr] = (half_t)v.y;
        T[c0 + j + 2][kr] = (half_t)v.z;
        T[c0 + j + 3][kr] = (half_t)v.w;
    }
    __syncthreads();
    const int nr = t >> 2, kc = (t & 3) << 4;
    if (!IMG) {
        half_t* dst = Wt + (size_t)(n0 + nr) * KD + k0 + kc;
        *(int4*)dst       = *(const int4*)&T[nr][kc];
        *(int4*)(dst + 8) = *(const int4*)&T[nr][kc + 8];
    } else {
        // B-image: row = out-col n, tile (ntile, kt=by), slot-XOR by row&7
        const int n = n0 + nr;
        const int ntile = n >> 8, rr = n & 255;
        const int s0 = kc >> 3;                   // logical slots s0, s0+1
        half_t* base = Wt + ((size_t)(ntile * 16 + by) * 256 + rr) * 64;
        *(int4*)(base + ((s0 ^ (rr & 7)) << 3))       = *(const int4*)&T[nr][kc];
        *(int4*)(base + (((s0 + 1) ^ (rr & 7)) << 3)) = *(const int4*)&T[nr][kc + 8];
    }
}

__global__ __launch_bounds__(256) void prep(
    const float* __restrict__ x, half_t* __restrict__ xh,
    const float* __restrict__ c, half_t* __restrict__ ch,
    const float* __restrict__ xpe, const float* __restrict__ cpe,
    float* __restrict__ xct, float* __restrict__ xst,
    float* __restrict__ cct, float* __restrict__ cst,
    const float* __restrict__ Wq,  half_t* __restrict__ Wqt,
    const float* __restrict__ Wkv, half_t* __restrict__ Wkt,
    const float* __restrict__ Wp,  half_t* __restrict__ Wpt)
{
    const int bid = blockIdx.x, t = threadIdx.x;
    if (bid < 1024) {
        if (bid < 256)      wtile(Wq,  Wqt, DIMC, 1,     bid & 15,         bid >> 4,         t);
        else if (bid < 768) wtile(Wkv, Wkt, 2 * DIMC, 1, (bid - 256) & 31, (bid - 256) >> 5, t);
        else                wtile(Wp,  Wpt, DIMC, 0,     (bid - 768) & 15, (bid - 768) >> 4, t);
    } else if (bid < 7168) {
        const int nx = NB * NX * DIMC;
        const int i = ((bid - 1024) * 256 + t) * 8;
        h8 o;
        if (i < nx) {
            const float* s = x + i;
            float4 a = *(const float4*)(s);
            float4 b = *(const float4*)(s + 4);
            o[0] = (half_t)a.x; o[1] = (half_t)a.y; o[2] = (half_t)a.z; o[3] = (half_t)a.w;
            o[4] = (half_t)b.x; o[5] = (half_t)b.y; o[6] = (half_t)b.z; o[7] = (half_t)b.w;
            // A-image for Q GEMM: tile (mt, kt), row r, slot-XOR
            const int R = i >> 10, k = i & 1023;
            const int mt = R >> 8, r = R & 255, kt = k >> 6, sl = (k & 63) >> 3;
            *(h8*)(xh + ((size_t)(mt * 16 + kt) * 256 + r) * 64 + ((sl ^ (r & 7)) << 3)) = o;
        } else {
            const int j = i - nx;                 // flat idx into c (8192 x 1024)
            const float* s = c + j;
            float4 a = *(const float4*)(s);
            float4 b = *(const float4*)(s + 4);
            o[0] = (half_t)a.x; o[1] = (half_t)a.y; o[2] = (half_t)a.z; o[3] = (half_t)a.w;
            o[4] = (half_t)b.x; o[5] = (half_t)b.y; o[6] = (half_t)b.z; o[7] = (half_t)b.w;
            const int R = j >> 10, k = j & 1023;
            const int mt = R >> 8, r = R & 255, kt = k >> 6, sl = (k & 63) >> 3;
            *(h8*)(ch + ((size_t)(mt * 16 + kt) * 256 + r) * 64 + ((sl ^ (r & 7)) << 3)) = o;
        }
    } else {
        const int i = (bid - 7168) * 256 + t;
        if (i < NX * HD) {
            const float th = xpe[i];
            xct[i] = cosf(th); xst[i] = sinf(th);
        } else {
            const int j = i - NX * HD;
            const float th = cpe[j];
            cct[j] = cosf(th); cst[j] = sinf(th);
        }
    }
}

// ---------------------------------------------------------------------------
// fp16 MFMA GEMM (proj only): BM=128, BK=64, 4 waves, dbuf + counted vmcnt.
// BN=64: 4x1 waves (32x64 each). MODE 2: + bias -> fp32 out row-major.
// ---------------------------------------------------------------------------
template <int MODE, int BN>
__global__ __launch_bounds__(256) void hgemm(
    const half_t* __restrict__ Ag, const half_t* __restrict__ Bt,
    const float* __restrict__ ct, const float* __restrict__ st,
    const float* __restrict__ bias,
    void* __restrict__ out0, void* __restrict__ out1)
{
    constexpr int MI = (BN == 128) ? 4 : 2;
    constexpr int BLOADS = BN / 32;
    __shared__ half_t As[2][8192];
    __shared__ half_t Bs[2][BN * 64];

    const int tid = threadIdx.x;
    const int w = tid >> 6, lane = tid & 63;
    const int lr = lane & 15, lg = lane >> 4;
    const int wrOff = (BN == 128) ? (w >> 1) * 64 : w * 32;
    const int wcOff = (BN == 128) ? (w & 1) * 64 : 0;

    int lin = (int)blockIdx.x;
    lin = (lin & 7) * ((int)gridDim.x >> 3) + (lin >> 3);
    const int m0 = (lin >> 4) * 128, n0 = (lin & 15) * BN;

    f32x4 acc[MI][4];
#pragma unroll
    for (int i = 0; i < MI; ++i)
#pragma unroll
        for (int j = 0; j < 4; ++j) acc[i][j] = f32x4{0.f, 0.f, 0.f, 0.f};

    size_t gA[4], gB[BLOADS];
    int loff[4];
#pragma unroll
    for (int c = 0; c < 4; ++c) {
        const int L = c * 4096 + w * 1024 + lane * 16;
        const int row = L >> 7;
        const int ss = ((L >> 4) & 7) ^ (row & 7);
        gA[c] = (size_t)(m0 + row) * KD + ss * 8;
        if (c < BLOADS) gB[c] = (size_t)(n0 + row) * KD + ss * 8;
        loff[c] = c * 2048 + w * 512;
    }

#define HSTAGE(buf, kk) do {                                               \
        _Pragma("unroll")                                                  \
        for (int c = 0; c < 4; ++c) {                                      \
            gload_lds16(Ag + gA[c] + (kk) * 64, &As[buf][loff[c]]);        \
            if (c < BLOADS) gload_lds16(Bt + gB[c] + (kk) * 64, &Bs[buf][loff[c]]); \
        }                                                                  \
    } while (0)

    HSTAGE(0, 0);
    asm volatile("s_waitcnt vmcnt(0)" ::: "memory");
    __builtin_amdgcn_s_barrier();
    __builtin_amdgcn_sched_barrier(0);

    for (int k = 0; k < KD / 64; ++k) {
        const int cb = k & 1;
        if (k + 1 < KD / 64) {
            HSTAGE(cb ^ 1, k + 1);
            if constexpr (BLOADS == 4)
                asm volatile("s_waitcnt vmcnt(8)" ::: "memory");
            else
                asm volatile("s_waitcnt vmcnt(6)" ::: "memory");
        } else {
            asm volatile("s_waitcnt vmcnt(0)" ::: "memory");
        }
        __builtin_amdgcn_s_barrier();
        __builtin_amdgcn_sched_barrier(0);

        __builtin_amdgcn_s_setprio(1);
#pragma unroll
        for (int kc = 0; kc < 2; ++kc) {
            h8 af[MI], bf[4];
#pragma unroll
            for (int mi = 0; mi < MI; ++mi) {
                const int r = wrOff + mi * 16 + lr;
                af[mi] = *(const h8*)&As[cb][r * 64 + (((kc * 4 + lg) ^ (r & 7)) << 3)];
            }
#pragma unroll
            for (int ni = 0; ni < 4; ++ni) {
                const int r = wcOff + ni * 16 + lr;
                bf[ni] = *(const h8*)&Bs[cb][r * 64 + (((kc * 4 + lg) ^ (r & 7)) << 3)];
            }
#pragma unroll
            for (int mi = 0; mi < MI; ++mi)
#pragma unroll
                for (int ni = 0; ni < 4; ++ni)
                    acc[mi][ni] = __builtin_amdgcn_mfma_f32_16x16x32_f16(
                        af[mi], bf[ni], acc[mi][ni], 0, 0, 0);
        }
        __builtin_amdgcn_s_setprio(0);

        __builtin_amdgcn_s_barrier();
        __builtin_amdgcn_sched_barrier(0);
    }
#undef HSTAGE

    if (MODE == 2) {
        float* o = (float*)out0;
#pragma unroll
        for (int ni = 0; ni < 4; ++ni) {
            const int col = n0 + ni * 16 + lr;
            const float bv = bias[col];
#pragma unroll
            for (int mi = 0; mi < MI; ++mi)
#pragma unroll
                for (int r = 0; r < 4; ++r) {
                    const int row = m0 + wrOff + mi * 16 + lg * 4 + r;
                    o[(size_t)row * DIMC + col] = acc[mi][ni][r] + bv;
                }
        }
    }
}

// ---------------------------------------------------------------------------
// MERGED GEMM v2.1: BM=256 x BN=128 tiles, 512 threads = 8 waves (4M x 2N,
// 64x64 out each). A double-buffered (32KB x2), B SINGLE-buffered (16KB).
// LDS 80KB -> 2 blocks/CU. Grid 640 = 512 KV + 128 Q blocks.
// Per K-tile: 4 phases x 8 MFMA. Staging at phases 0-1; phase-3 vmcnt(0)
// gate (required: A-halves are consumed per-WAVE, all 6 loads must retire
// before next P0). NOTE: 2-phase merge (R29) spills acc to scratch
// (+31 MB traffic, -26 µs regression) -- 4 phases is the pressure valve.
// ---------------------------------------------------------------------------
__global__ __launch_bounds__(512, 4) void hgemm_all(
    const half_t* __restrict__ Aimg, const half_t* __restrict__ Bimg,
    const half_t* __restrict__ Aq,   const half_t* __restrict__ Bq,
    const float* __restrict__ cct, const float* __restrict__ cst,
    const float* __restrict__ xct, const float* __restrict__ xst,
    half_t* __restrict__ Kw, half_t* __restrict__ Vw, half_t* __restrict__ Qw)
{
    __shared__ half_t lds[40960];   // 80 KB: A0@0, A1@16384, B@32768

    const int tid = threadIdx.x;
    const int w = tid >> 6, lane = tid & 63;
    const int lr = lane & 15, lg = lane >> 4;
    const int wr = w >> 1, wc = w & 1;
    const int wrOff = wr * 64, wcOff = wc * 64;

    const int bid = (int)blockIdx.x;
    const bool isQ = bid >= 512;
    int m0, n0;
    const half_t* Ablk;
    const half_t* Bblk;
    if (!isQ) {
        int lin = (bid & 7) * 64 + (bid >> 3);   // 512 blocks, bijective
        const int mt = lin >> 4, nt = lin & 15;
        m0 = mt * 256; n0 = nt * 128;
        Ablk = Aimg + (size_t)mt * 262144;
        Bblk = Bimg + (size_t)(nt >> 1) * 262144 + (size_t)(nt & 1) * 8192;
    } else {
        const int q = bid - 512;                 // 128 blocks
        int lin = (q & 7) * 16 + (q >> 3);       // bijective (128 % 8 == 0)
        const int mt = lin >> 3, nt = lin & 7;
        m0 = mt * 256; n0 = nt * 128;
        Ablk = Aq + (size_t)mt * 262144;
        Bblk = Bq + (size_t)(nt >> 1) * 262144 + (size_t)(nt & 1) * 8192;
    }
    const int so2 = w * 512 + lane * 8;

    f32x4 acc[4][4];
#pragma unroll
    for (int i = 0; i < 4; ++i)
#pragma unroll
        for (int j = 0; j < 4; ++j) acc[i][j] = f32x4{0.f, 0.f, 0.f, 0.f};
    h8 af[2];       // [kc] for the current mi
    h8 bf[4][2];    // [ni][kc], held per K-tile

// one 8KB chunk (512 thr x 16B) per call
#define ISSUEH(SRC, DSTOFF) do {                                     \
        gload_lds16((SRC) + so2,        &lds[(DSTOFF) + w * 512]);   \
        gload_lds16((SRC) + 4096 + so2, &lds[(DSTOFF) + 4096 + w * 512]); \
    } while (0)

#define PHASE(MI0, AOFF, READBF, STG, GATE) do {                     \
        {                                                            \
            const int r_ = wrOff + (MI0) * 16 + lr;                  \
            _Pragma("unroll")                                        \
            for (int kc = 0; kc < 2; ++kc)                           \
                af[kc] = *(const h8*)&lds[(AOFF) + r_ * 64 + (((kc * 4 + lg) ^ (r_ & 7)) << 3)]; \
        }                                                            \
        if (READBF) {                                                \
            _Pragma("unroll")                                        \
            for (int ni = 0; ni < 4; ++ni)                           \
            _Pragma("unroll")                                        \
            for (int kc = 0; kc < 2; ++kc) {                         \
                const int rb = wcOff + ni * 16 + lr;                 \
                bf[ni][kc] = *(const h8*)&lds[32768 + rb * 64 + (((kc * 4 + lg) ^ (rb & 7)) << 3)]; \
            }                                                        \
        }                                                            \
        STG;                                                         \
        __builtin_amdgcn_sched_barrier(0);                           \
        __builtin_amdgcn_s_barrier();                                \
        __builtin_amdgcn_s_setprio(1);                               \
        _Pragma("unroll")                                            \
        for (int ni = 0; ni < 4; ++ni)                               \
        _Pragma("unroll")                                            \
        for (int kc = 0; kc < 2; ++kc)                               \
            acc[(MI0)][ni] = __builtin_amdgcn_mfma_f32_16x16x32_f16( \
                af[kc], bf[ni][kc], acc[(MI0)][ni], 0, 0, 0);        \
        __builtin_amdgcn_s_setprio(0);                               \
        GATE;                                                        \
        __builtin_amdgcn_s_barrier();                                \
    } while (0)

#define GATE0 asm volatile("s_waitcnt vmcnt(0)" ::: "memory")
#define NOG   ((void)0)

    // prologue: A(0) -> A0 (2 chunks), B(0) -> B
    ISSUEH(Ablk, 0);
    ISSUEH(Ablk + 8192, 8192);
    ISSUEH(Bblk, 32768);
    asm volatile("s_waitcnt vmcnt(0)" ::: "memory");
    __builtin_amdgcn_s_barrier();
    __builtin_amdgcn_sched_barrier(0);

#pragma unroll 2
    for (int t = 0; t < 16; ++t) {
        const int AOFF = (t & 1) ? 16384 : 0;
        const int ALT  = (t & 1) ? 0 : 16384;
        const half_t* An = Ablk + (size_t)(t + 1) * 16384;
        const half_t* Bn = Bblk + (size_t)(t + 1) * 16384;
        const bool more = (t + 1 < 16);
        // v2.1: issue all staging in phases 0-1 so loads land during 2-3.
        PHASE(0, AOFF, true,  if (more) ISSUEH(An, ALT),                  NOG);
        PHASE(1, AOFF, false,
              if (more) { ISSUEH(Bn, 32768); ISSUEH(An + 8192, ALT + 8192); },
              NOG);
        PHASE(2, AOFF, false, NOG,                                        NOG);
        PHASE(3, AOFF, false, NOG,                                        GATE0);
    }
#undef PHASE
#undef ISSUEH
#undef GATE0
#undef NOG

    if (!isQ) {
        // KV epilogue: RoPE-K (cols < 1024) / V tile images for attention
        const bool isK = (n0 < DIMC);
        const int h = ((n0 & (DIMC - 1)) >> 6) + wc;
#pragma unroll
        for (int mi = 0; mi < 4; ++mi)
#pragma unroll
            for (int r = 0; r < 4; ++r) {
                const int row = m0 + wrOff + mi * 16 + lg * 4 + r;
                const int bb = row >> 11, nn = row & (NC - 1);
                const int tt = nn >> 6, rr = nn & 63;
                const size_t tbase = ((size_t)(bb * NHEAD + h) * 32 + tt) * 4096;
                const float* cr = cct + nn * HD;
                const float* sr = cst + nn * HD;
#pragma unroll
                for (int ni = 0; ni < 4; ++ni) {
                    const int d = ni * 16 + lr;
                    const float val = acc[mi][ni][r];
                    if (isK) {
                        const float pv = acc[mi][ni ^ 2][r];
                        Kw[tbase + rr * 64 + ((((d >> 3) ^ (rr & 7)) << 3) | (d & 7))] =
                            (half_t)(val * cr[d] + (ni < 2 ? -pv : pv) * sr[d]);
                    } else {
                        Vw[tbase + d * 64 + ((((rr >> 3) ^ (d & 7)) << 3) | (rr & 7))] =
                            (half_t)val;
                    }
                }
            }
    } else {
        // Q epilogue: RoPE * QSCALE -> fp16 (B, H, NX, HD)
        const int h = (n0 >> 6) + wc;
#pragma unroll
        for (int mi = 0; mi < 4; ++mi)
#pragma unroll
            for (int r = 0; r < 4; ++r) {
                const int row = m0 + wrOff + mi * 16 + lg * 4 + r;
                const int bb = row >> 10, nn = row & (NX - 1);
                const float* cr = xct + nn * HD;
                const float* sr = xst + nn * HD;
                half_t* op = Qw + (((size_t)(bb * NHEAD + h)) * NX + nn) * HD;
#pragma unroll
                for (int ni = 0; ni < 4; ++ni) {
                    const int d = ni * 16 + lr;
                    const float val = acc[mi][ni][r];
                    const float pv  = acc[mi][ni ^ 2][r];   // d ^ 32 partner
                    op[d] = (half_t)((val * cr[d] + (ni < 2 ? -pv : pv) * sr[d]) * QSCALE);
                }
            }
    }
}

// ---------------------------------------------------------------------------
// Swapped-operand MFMA flash attention (fp16), fixed-max softmax, kv-SPLIT,
// 4 waves, QBLK=256 (4 q-fragments/wave, K/V frags read once). 3-deep K/V
// ring, ONE barrier per tile. Partials out IN FP16 (halves the Opart
// round-trip traffic; |acc| << fp16 range).
// ---------------------------------------------------------------------------
__global__ __launch_bounds__(256) void attn_mfma(
    const half_t* __restrict__ Q, const half_t* __restrict__ Kg,
    const half_t* __restrict__ Vg,
    half_t* __restrict__ Opart, float* __restrict__ Lpart)
{
    __shared__ half_t Ks[3][4096];   // swizzled K tile image [kv][d]
    __shared__ half_t Vs[3][4096];   // swizzled V^T tile image [d][kv]
    __shared__ half_t Ps[16384];     // swizzled P [q(256)][kv], wave-private rows

    const int tid = threadIdx.x;
    const int w = tid >> 6, lane = tid & 63;
    const int lr = lane & 15, lg = lane >> 4;
    const int e7 = lr & 7;

    // kv half + XCD swizzle (both halves of a bh land on the same XCD)
    const int inner = (int)blockIdx.x & 255;
    const int kvh = (int)blockIdx.x >> 8;
    const int sid = (inner & 7) * 32 + (inner >> 3);
    const int bh = sid >> 2;
    const int q0 = (sid & 3) * 256;

    // Q fragments: qb in 0..3, rows q0 + qb*64 + w*16 + lr
    h8 qf0[4], qf1[4];
#pragma unroll
    for (int qb = 0; qb < 4; ++qb) {
        const half_t* qbase =
            Q + ((size_t)bh * NX + q0 + qb * 64 + w * 16 + lr) * HD + lg * 8;
        qf0[qb] = *(const h8*)(qbase);
        qf1[qb] = *(const h8*)(qbase + 32);
    }

    f32x4 acc[4][4];
#pragma unroll
    for (int qb = 0; qb < 4; ++qb)
#pragma unroll
        for (int i = 0; i < 4; ++i) acc[qb][i] = f32x4{0.f, 0.f, 0.f, 0.f};
    f32x4 accl[4];
#pragma unroll
    for (int qb = 0; qb < 4; ++qb) accl[qb] = f32x4{0.f, 0.f, 0.f, 0.f};

    h8 vone;
#pragma unroll
    for (int i = 0; i < 8; ++i) vone[i] = (half_t)(lr == 0 ? 1.0f : 0.0f);

    const half_t* Kt = Kg + (size_t)bh * 32 * 4096;
    const half_t* Vt = Vg + (size_t)bh * 32 * 4096;
    const int so = w * 512 + lane * 8;   // 256 thr cover 2048; two rounds/tile
    const int t0 = kvh * 16;

#define STAGE(bi, t) do {                                           \
        const half_t* kg_ = Kt + (size_t)(t) * 4096;                \
        const half_t* vg_ = Vt + (size_t)(t) * 4096;                \
        gload_lds16(kg_ + so,        &Ks[bi][w * 512]);             \
        gload_lds16(kg_ + 2048 + so, &Ks[bi][2048 + w * 512]);      \
        gload_lds16(vg_ + so,        &Vs[bi][w * 512]);             \
        gload_lds16(vg_ + 2048 + so, &Vs[bi][2048 + w * 512]);      \
    } while (0)

    // prologue: issue STAGE(tile 0) into buf 0 (no drain; gated in body 0)
    STAGE(0, t0);

    const int rowq = w * 16 + lr;     // base q row; qb adds qb*64

    int cur = 0, nxt = 1;
    for (int i = 0; i < 16; ++i) {
        if (i + 1 < 16) {
            STAGE(nxt, t0 + i + 1);
            asm volatile("s_waitcnt vmcnt(4)" ::: "memory");
        } else {
            asm volatile("s_waitcnt vmcnt(0)" ::: "memory");
        }
        __builtin_amdgcn_s_barrier();
        __builtin_amdgcn_sched_barrier(0);

        // K fragments read ONCE, reused for all 4 qb
        h8 kfr[4][2];
#pragma unroll
        for (int cb = 0; cb < 4; ++cb) {
            const int r = cb * 16 + lr;
            kfr[cb][0] = *(const h8*)&Ks[cur][r * 64 + ((lg ^ e7) << 3)];
            kfr[cb][1] = *(const h8*)&Ks[cur][r * 64 + (((4 + lg) ^ e7) << 3)];
        }

#pragma unroll
        for (int qb = 0; qb < 4; ++qb) {
            const int rowp = qb * 64 + rowq;

            // S^T = K Q^T, C-init = NEGM. Lane: q=lr, kv = cb*16+lg*4+r.
            f32x4 sc[4];
            __builtin_amdgcn_s_setprio(1);
#pragma unroll
            for (int cb = 0; cb < 4; ++cb) {
                f32x4 a = {NEGM, NEGM, NEGM, NEGM};
                a = __builtin_amdgcn_mfma_f32_16x16x32_f16(kfr[cb][0], qf0[qb], a, 0, 0, 0);
                a = __builtin_amdgcn_mfma_f32_16x16x32_f16(kfr[cb][1], qf1[qb], a, 0, 0, 0);
                sc[cb] = a;
            }
            __builtin_amdgcn_s_setprio(0);

            // p = exp2(s), packed to fp16; P^T -> Ps rows [rowp]
#pragma unroll
            for (int cb = 0; cb < 4; ++cb) {
                fp16x2 a01 = __builtin_amdgcn_cvt_pkrtz(exp2f(sc[cb][0]), exp2f(sc[cb][1]));
                fp16x2 a23 = __builtin_amdgcn_cvt_pkrtz(exp2f(sc[cb][2]), exp2f(sc[cb][3]));
                union { h4 h; uint2 u; } pw;
                pw.u.x = *(unsigned int*)&a01;
                pw.u.y = *(unsigned int*)&a23;
                const int s = cb * 2 + (lg >> 1);
                *(h4*)&Ps[rowp * 64 + ((s ^ e7) << 3) + (lg & 1) * 4] = pw.h;
            }
        }

        // P fragments for all qb; V fragments read once per db
        h8 pf0q[4], pf1q[4];
#pragma unroll
        for (int qb = 0; qb < 4; ++qb) {
            const int rowp = qb * 64 + rowq;
            pf0q[qb] = *(const h8*)&Ps[rowp * 64 + ((lg ^ e7) << 3)];
            pf1q[qb] = *(const h8*)&Ps[rowp * 64 + (((4 + lg) ^ e7) << 3)];
        }

        __builtin_amdgcn_s_setprio(1);
#pragma unroll
        for (int db = 0; db < 4; ++db) {
            const int rd = db * 16 + lr;
            const h8 vf0 = *(const h8*)&Vs[cur][rd * 64 + ((lg ^ e7) << 3)];
            const h8 vf1 = *(const h8*)&Vs[cur][rd * 64 + (((4 + lg) ^ e7) << 3)];
#pragma unroll
            for (int qb = 0; qb < 4; ++qb) {
                acc[qb][db] = __builtin_amdgcn_mfma_f32_16x16x32_f16(pf0q[qb], vf0, acc[qb][db], 0, 0, 0);
                acc[qb][db] = __builtin_amdgcn_mfma_f32_16x16x32_f16(pf1q[qb], vf1, acc[qb][db], 0, 0, 0);
            }
        }
#pragma unroll
        for (int qb = 0; qb < 4; ++qb) {
            accl[qb] = __builtin_amdgcn_mfma_f32_16x16x32_f16(pf0q[qb], vone, accl[qb], 0, 0, 0);
            accl[qb] = __builtin_amdgcn_mfma_f32_16x16x32_f16(pf1q[qb], vone, accl[qb], 0, 0, 0);
        }
        __builtin_amdgcn_s_setprio(0);

        // advance 3-deep ring (no end-of-tile barrier: WAR protected by the
        // pre-compute barrier one iteration later)
        cur = nxt;
        nxt = (nxt == 2) ? 0 : nxt + 1;
    }
#undef STAGE

    // write partials (fp16): per qb a 64q x 64d tile + f32 row sums (lr==0).
#pragma unroll
    for (int qb = 0; qb < 4; ++qb) {
        const int qblk = (q0 >> 6) + qb;
        const int slot = (bh * 16 + qblk) * 2 + kvh;
        half_t* Po = Opart + (size_t)slot * 4096;
#pragma unroll
        for (int db = 0; db < 4; ++db)
#pragma unroll
            for (int r = 0; r < 4; ++r)
                Po[(w * 16 + lg * 4 + r) * 64 + db * 16 + lr] = (half_t)acc[qb][db][r];
        if (lr == 0) {
#pragma unroll
            for (int r = 0; r < 4; ++r)
                Lpart[(size_t)slot * 64 + w * 16 + lg * 4 + r] = accl[qb][r];
        }
    }
}

// ---------------------------------------------------------------------------
// Combine: O = (P0 + P1) / (l0 + l1) -> Ow fp16 (B, NX, DIMC) layout.
// Partials are fp16. 1024 blocks, 256 threads, 16 outputs each.
// ---------------------------------------------------------------------------
__global__ __launch_bounds__(256) void combine(
    const half_t* __restrict__ Opart, const float* __restrict__ Lpart,
    half_t* __restrict__ Ow)
{
    const int pidx = blockIdx.x;              // bh*16 + qblk
    const int bh = pidx >> 4, qblk = pidx & 15;
    const int b = bh >> 4, h = bh & 15;
    const int t = threadIdx.x;
    const int row = t >> 2;                   // 0..63
    const int c0 = (t & 3) << 4;              // 0,16,32,48

    const half_t* P0 = Opart + (size_t)(pidx * 2 + 0) * 4096 + row * 64 + c0;
    const half_t* P1 = Opart + (size_t)(pidx * 2 + 1) * 4096 + row * 64 + c0;
    const float inv = 1.f / (Lpart[(size_t)(pidx * 2 + 0) * 64 + row] +
                             Lpart[(size_t)(pidx * 2 + 1) * 64 + row]);

    half_t* o = Ow + ((size_t)b * NX + qblk * 64 + row) * DIMC + h * 64 + c0;
#pragma unroll
    for (int j = 0; j < 16; j += 8) {
        h8 a = *(const h8*)(P0 + j);
        h8 bb = *(const h8*)(P1 + j);
        h8 ov;
#pragma unroll
        for (int k = 0; k < 8; ++k)
            ov[k] = (half_t)(((float)a[k] + (float)bb[k]) * inv);
        *(h8*)(o + j) = ov;
    }
}

// ---------------------------------------------------------------------------
extern "C" void kernel_launch(void* const* d_in, const int* in_sizes, int n_in,
                              void* d_out, int out_size, void* d_ws, size_t ws_size,
                              hipStream_t stream)
{
    const float* x     = (const float*)d_in[0];
    const float* c     = (const float*)d_in[1];
    const float* xpe   = (const float*)d_in[2];
    const float* cpe   = (const float*)d_in[3];
    const float* Wq    = (const float*)d_in[4];
    const float* Wkv   = (const float*)d_in[5];
    const float* Wproj = (const float*)d_in[6];
    const float* bproj = (const float*)d_in[7];

    char* wsb = (char*)d_ws;
    half_t* xh  = (half_t*)(wsb);                          // 8 MB  (A-image, dead by attn)
    half_t* ch  = (half_t*)(wsb + ((size_t)8  << 20));     // 16 MB (A-image, dead by attn)
    half_t* Wqt = (half_t*)(wsb + ((size_t)24 << 20));     // 2 MB  (B-image, dead by attn)
    half_t* Wkt = (half_t*)(wsb + ((size_t)26 << 20));     // 4 MB  (B-image, dead by attn)
    half_t* Kw  = (half_t*)(wsb + ((size_t)32 << 20));     // 16 MB (attn image)
    half_t* Vw  = (half_t*)(wsb + ((size_t)48 << 20));     // 16 MB (attn image)
    half_t* Ow  = (half_t*)(wsb + ((size_t)64 << 20));     // 8 MB
    float*  xct = (float*)(wsb + ((size_t)72 << 20));      // 256 KB
    float*  xst = (float*)(wsb + ((size_t)72 << 20) + (256u << 10));
    float*  cct = (float*)(wsb + ((size_t)72 << 20) + (512u << 10));
    float*  cst = (float*)(wsb + ((size_t)72 << 20) + (1024u << 10));
    half_t* Wpt = (half_t*)(wsb + ((size_t)74 << 20));     // 2 MB (live past attn)
    float*  Lpart = (float*)(wsb + ((size_t)76 << 20));    // 512 KB
    half_t* OpartH = (half_t*)(wsb);                       // 16 MB over dead xh/ch
    half_t* Qw  = (half_t*)d_out;   // attn consumes before hgemm<2> overwrites

    prep<<<7936, 256, 0, stream>>>(x, xh, c, ch, xpe, cpe,
                                   xct, xst, cct, cst,
                                   Wq, Wqt, Wkv, Wkt, Wproj, Wpt);

    hgemm_all<<<640, 512, 0, stream>>>(ch, Wkt, xh, Wqt,
                                       cct, cst, xct, xst,
                                       Kw, Vw, Qw);
    attn_mfma<<<512, 256, 0, stream>>>(Qw, Kw, Vw, OpartH, Lpart);
    combine<<<1024, 256, 0, stream>>>(OpartH, Lpart, Ow);
    hgemm<2, 64><<<512, 256, 0, stream>>>(Ow, Wpt, nullptr, nullptr, bproj,
                                          (float*)d_out, nullptr);
}